// Round 1
// baseline (225.111 us; speedup 1.0000x reference)
//
#include <hip/hip_runtime.h>

// ---------------------------------------------------------------------------
// MusicGenerationV2: two zero-state LSTM cells.
//   time:  gates = x @ W_ih_t^T + (b_ih_t+b_hh_t); to = sig(o)*tanh(sig(i)*tanh(g))
//   note:  gates = note_in @ W_ih_n^T + (b_ih_n+b_hh_n); y = (sig(o)*tanh(sig(i)*tanh(g)) > 0.5)
// note_in[row][t*64+h] = to[t][row][h], row = note*1024+b  (plain index transpose).
// Fully fused MFMA pipeline, fp16 split-precision (hi+lo, 3 products) = fp32-level accuracy.
// ---------------------------------------------------------------------------

typedef _Float16 half8  __attribute__((ext_vector_type(8)));
typedef _Float16 half4v __attribute__((ext_vector_type(4)));
typedef float    f32x4  __attribute__((ext_vector_type(4)));

#define T_STEPS 128
#define NBROWS  12288      // 12 notes * 1024 batch
#define ROWS_WG 128        // rows per workgroup (4 waves x 32 rows)
#define NRT     96         // NBROWS / ROWS_WG

// LDS strides (halves). Padded to keep ds_read_b128 16B-aligned and <=2-way banked.
#define XS_STRIDE 40       // x tile  [128][40], k=0..23 data, 24..31 zero pad
#define TO_STRIDE 72       // to tile [128][72], h=0..63
#define WN_STRIDE 72       // Wn tile [96][72],  k=0..63

__device__ inline f32x4 mfma16(half8 a, half8 b, f32x4 c) {
  return __builtin_amdgcn_mfma_f32_16x16x32_f16(a, b, c, 0, 0, 0);
}
__device__ inline float sigf(float z) {
  float e = __builtin_amdgcn_exp2f(-1.44269504088896341f * z);
  return __builtin_amdgcn_rcpf(1.0f + e);
}
__device__ inline float tanhfast(float z) {
  // tanh(z) = 1 - 2/(exp(2z)+1); safe at +/-inf of exp
  float e = __builtin_amdgcn_exp2f(2.88539008177792681f * z);
  return 1.0f - 2.0f * __builtin_amdgcn_rcpf(1.0f + e);
}

// ---------------------------------------------------------------------------
// Kernel 0: split weights into fp16 hi/lo.
// WselPerm[c][k], c in [0,192): block = c/64 -> gate {i,g,o} (f skipped, c_prev=0),
//   within block: cl=(c%64)&15, ctw=(c%64)>>4, h = cl*4+ctw  (permutation so that
//   each MFMA lane's 4 gate-columns (ctw=0..3) are 4 consecutive h -> half4 LDS writes).
// ---------------------------------------------------------------------------
__global__ __launch_bounds__(256) void k0_prep(
    const float* __restrict__ W_ih_t, const float* __restrict__ b_ih_t,
    const float* __restrict__ b_hh_t, const float* __restrict__ W_ih_n,
    _Float16* __restrict__ wsel_hi, _Float16* __restrict__ wsel_lo,
    float* __restrict__ biasp,
    _Float16* __restrict__ wn_hi, _Float16* __restrict__ wn_lo)
{
  int id = blockIdx.x * 256 + threadIdx.x;
  if (id < 192 * 32) {
    int c = id >> 5, k = id & 31;
    int blk = c >> 6, ci = c & 63;
    int cl = ci & 15, ctw = ci >> 4;
    int h = cl * 4 + ctw;
    int grow = (blk == 0 ? 0 : (blk == 1 ? 128 : 192)) + h;  // i,g,o rows of W_ih_t
    float v = (k < 24) ? W_ih_t[grow * 24 + k] : 0.0f;
    _Float16 hi = (_Float16)v;
    wsel_hi[id] = hi;
    wsel_lo[id] = (_Float16)(v - (float)hi);
    if (k == 0) biasp[c] = b_ih_t[grow] + b_hh_t[grow];
  }
  for (int f = id; f < 96 * 8192; f += gridDim.x * 256) {
    float v = W_ih_n[f];
    _Float16 hi = (_Float16)v;
    wn_hi[f] = hi;
    wn_lo[f] = (_Float16)(v - (float)hi);
  }
}

// ---------------------------------------------------------------------------
// Kernel 1: fused time-LSTM + note-GEMM partial sums.
// grid = NRT * tsplit blocks of 256 threads (4 waves, 32 rows each).
// ---------------------------------------------------------------------------
__global__ __launch_bounds__(256, 1) void k1_time_note(
    const float* __restrict__ x,
    const _Float16* __restrict__ wsel_hi, const _Float16* __restrict__ wsel_lo,
    const float* __restrict__ biasp,
    const _Float16* __restrict__ wn_hi, const _Float16* __restrict__ wn_lo,
    float* __restrict__ partials, int tchunk)
{
  extern __shared__ _Float16 lds[];
  _Float16* xs_hi  = lds;                         // [128][XS_STRIDE]
  _Float16* xs_lo  = xs_hi  + ROWS_WG * XS_STRIDE;
  _Float16* tos_hi = xs_lo  + ROWS_WG * XS_STRIDE;  // [128][TO_STRIDE]
  _Float16* tos_lo = tos_hi + ROWS_WG * TO_STRIDE;
  _Float16* wns_hi = tos_lo + ROWS_WG * TO_STRIDE;  // [96][WN_STRIDE]
  _Float16* wns_lo = wns_hi + 96 * WN_STRIDE;

  const int tid = threadIdx.x;
  const int l   = tid & 63;
  const int w   = tid >> 6;     // wave 0..3, owns rows [w*32, w*32+32)
  const int cl  = l & 15;
  const int kg  = l >> 4;       // 0..3

  const int rt   = blockIdx.x % NRT;
  const int ts   = blockIdx.x / NRT;
  const int row0 = rt * ROWS_WG;
  const int t0   = ts * tchunk;

  // zero the x k-pad (k = 24..31) once
  if (tid < ROWS_WG) {
    half8 z = {0, 0, 0, 0, 0, 0, 0, 0};
    *(half8*)(xs_hi + tid * XS_STRIDE + 24) = z;
    *(half8*)(xs_lo + tid * XS_STRIDE + 24) = z;
  }

  // W_ih_t fragments: register-resident for the whole kernel.
  // B-frag for 16x16x32: lane holds B[kg*8+j][cl] = WselPerm[ct*16+cl][kg*8+j]
  half8 wth[12], wtl[12];
#pragma unroll
  for (int ct = 0; ct < 12; ++ct) {
    int off = (ct * 16 + cl) * 32 + kg * 8;
    wth[ct] = *(const half8*)(wsel_hi + off);
    wtl[ct] = *(const half8*)(wsel_lo + off);
  }
  float bias[3][4];
#pragma unroll
  for (int blk = 0; blk < 3; ++blk)
#pragma unroll
    for (int ctw = 0; ctw < 4; ++ctw)
      bias[blk][ctw] = biasp[blk * 64 + ctw * 16 + cl];

  f32x4 nacc[2][6];
#pragma unroll
  for (int mt = 0; mt < 2; ++mt)
#pragma unroll
    for (int nt = 0; nt < 6; ++nt)
      nacc[mt][nt] = (f32x4){0.f, 0.f, 0.f, 0.f};

  const int srow = tid >> 1;            // x staging: 2 threads per row
  const int sch  = (tid & 1) * 12;

  for (int tt = 0; tt < tchunk; ++tt) {
    const int t = t0 + tt;

    // ---- issue global loads into registers (overlap with barrier wait) ----
    const float* gx = x + ((size_t)t * NBROWS + row0 + srow) * 24 + sch;
    f32x4 xv0 = *(const f32x4*)(gx + 0);
    f32x4 xv1 = *(const f32x4*)(gx + 4);
    f32x4 xv2 = *(const f32x4*)(gx + 8);

    half8 wv[6];
#pragma unroll
    for (int i = 0; i < 6; ++i) {
      int f = tid + 256 * i;
      int p = (f >= 768) ? 1 : 0;
      int nk = f - p * 768;
      int n = nk >> 3, c8 = nk & 7;
      const _Float16* src = (p ? wn_lo : wn_hi) + (size_t)n * 8192 + t * 64 + c8 * 8;
      wv[i] = *(const half8*)src;
    }

    __syncthreads();  // previous iteration's note-MFMA reads are done

    // ---- stage x (split f32 -> fp16 hi/lo) ----
    {
      half4v h0, h1, h2, q0, q1, q2;
#pragma unroll
      for (int j = 0; j < 4; ++j) {
        _Float16 a = (_Float16)xv0[j]; h0[j] = a; q0[j] = (_Float16)(xv0[j] - (float)a);
        _Float16 b = (_Float16)xv1[j]; h1[j] = b; q1[j] = (_Float16)(xv1[j] - (float)b);
        _Float16 c = (_Float16)xv2[j]; h2[j] = c; q2[j] = (_Float16)(xv2[j] - (float)c);
      }
      _Float16* dh = xs_hi + srow * XS_STRIDE + sch;
      *(half4v*)(dh + 0) = h0; *(half4v*)(dh + 4) = h1; *(half4v*)(dh + 8) = h2;
      _Float16* dl = xs_lo + srow * XS_STRIDE + sch;
      *(half4v*)(dl + 0) = q0; *(half4v*)(dl + 4) = q1; *(half4v*)(dl + 8) = q2;
    }
    // ---- stage Wn slice [96][64] hi/lo ----
#pragma unroll
    for (int i = 0; i < 6; ++i) {
      int f = tid + 256 * i;
      int p = (f >= 768) ? 1 : 0;
      int nk = f - p * 768;
      int n = nk >> 3, c8 = nk & 7;
      _Float16* dst = (p ? wns_lo : wns_hi) + n * WN_STRIDE + c8 * 8;
      *(half8*)dst = wv[i];
    }

    __syncthreads();  // staging visible

    // ---- time MFMA: gates[32 rows x 192] per wave ----
    // A-frag: lane holds A[cl][kg*8+j] = x[row=w*32+mt*16+cl][k]
    half8 xah[2], xal[2];
#pragma unroll
    for (int mt = 0; mt < 2; ++mt) {
      int off = (w * 32 + mt * 16 + cl) * XS_STRIDE + kg * 8;
      xah[mt] = *(half8*)(xs_hi + off);
      xal[mt] = *(half8*)(xs_lo + off);
    }

    half4v pkh[2][4], pkl[2][4];   // [mt][r], element index = ctw (4 consecutive h)
#pragma unroll
    for (int ctw = 0; ctw < 4; ++ctw) {
      f32x4 g[2][3];
#pragma unroll
      for (int mt = 0; mt < 2; ++mt)
#pragma unroll
        for (int blk = 0; blk < 3; ++blk) {
          int c = blk * 4 + ctw;
          f32x4 a = (f32x4){0.f, 0.f, 0.f, 0.f};
          a = mfma16(xah[mt], wth[c], a);   // hi*hi
          a = mfma16(xah[mt], wtl[c], a);   // hi*lo
          a = mfma16(xal[mt], wth[c], a);   // lo*hi  (lo*lo ~2^-22, skipped)
          g[mt][blk] = a;
        }
#pragma unroll
      for (int mt = 0; mt < 2; ++mt)
#pragma unroll
        for (int r = 0; r < 4; ++r) {
          float zi = g[mt][0][r] + bias[0][ctw];
          float zg = g[mt][1][r] + bias[1][ctw];
          float zo = g[mt][2][r] + bias[2][ctw];
          float cc = sigf(zi) * tanhfast(zg);
          float to = sigf(zo) * tanhfast(cc);
          _Float16 hh = (_Float16)to;
          pkh[mt][r][ctw] = hh;
          pkl[mt][r][ctw] = (_Float16)(to - (float)hh);
        }
    }
    // write to-tile: lane owns (rows kg*4+r, h = cl*4 .. cl*4+3) -> b64 writes
#pragma unroll
    for (int mt = 0; mt < 2; ++mt)
#pragma unroll
      for (int r = 0; r < 4; ++r) {
        int row = w * 32 + mt * 16 + kg * 4 + r;
        *(half4v*)(tos_hi + row * TO_STRIDE + cl * 4) = pkh[mt][r];
        *(half4v*)(tos_lo + row * TO_STRIDE + cl * 4) = pkl[mt][r];
      }

    __syncthreads();  // to-tile ready

    // ---- note MFMA: nacc[32 rows x 96] += to[32 x 64] * WnT[64 x 96] ----
    half8 tah[2][2], tal[2][2];
#pragma unroll
    for (int mt = 0; mt < 2; ++mt)
#pragma unroll
      for (int kc = 0; kc < 2; ++kc) {
        int off = (w * 32 + mt * 16 + cl) * TO_STRIDE + kc * 32 + kg * 8;
        tah[mt][kc] = *(half8*)(tos_hi + off);
        tal[mt][kc] = *(half8*)(tos_lo + off);
      }
#pragma unroll
    for (int nt = 0; nt < 6; ++nt) {
#pragma unroll
      for (int kc = 0; kc < 2; ++kc) {
        int off = (nt * 16 + cl) * WN_STRIDE + kc * 32 + kg * 8;
        half8 bh = *(half8*)(wns_hi + off);
        half8 bl = *(half8*)(wns_lo + off);
#pragma unroll
        for (int mt = 0; mt < 2; ++mt) {
          nacc[mt][nt] = mfma16(tah[mt][kc], bh, nacc[mt][nt]);
          nacc[mt][nt] = mfma16(tah[mt][kc], bl, nacc[mt][nt]);
          nacc[mt][nt] = mfma16(tal[mt][kc], bh, nacc[mt][nt]);
        }
      }
    }
  }

  // ---- write partial note-gate sums ----
  float* pbase = partials + (size_t)ts * NBROWS * 96;
#pragma unroll
  for (int mt = 0; mt < 2; ++mt)
#pragma unroll
    for (int nt = 0; nt < 6; ++nt)
#pragma unroll
      for (int r = 0; r < 4; ++r) {
        int row = row0 + w * 32 + mt * 16 + kg * 4 + r;
        int col = nt * 16 + cl;
        pbase[(size_t)row * 96 + col] = nacc[mt][nt][r];
      }
}

// ---------------------------------------------------------------------------
// Kernel 2: reduce tsplit partials, note activations, threshold.
// ---------------------------------------------------------------------------
__global__ __launch_bounds__(256) void k2_note_out(
    const float* __restrict__ partials,
    const float* __restrict__ b_ih_n, const float* __restrict__ b_hh_n,
    float* __restrict__ out, int tsplit)
{
  int idx = blockIdx.x * 256 + threadIdx.x;
  if (idx >= NBROWS * 24) return;
  int row = idx / 24, jj = idx - row * 24;
  float gi = 0.f, gg = 0.f, go = 0.f;
  for (int p = 0; p < tsplit; ++p) {
    const float* pp = partials + ((size_t)p * NBROWS + row) * 96;
    gi += pp[jj];
    gg += pp[48 + jj];
    go += pp[72 + jj];
  }
  gi += b_ih_n[jj]      + b_hh_n[jj];
  gg += b_ih_n[48 + jj] + b_hh_n[48 + jj];
  go += b_ih_n[72 + jj] + b_hh_n[72 + jj];
  float si = 1.f / (1.f + expf(-gi));
  float so = 1.f / (1.f + expf(-go));
  float v = so * tanhf(si * tanhf(gg));
  out[idx] = (v > 0.5f) ? 1.0f : 0.0f;
}

// ---------------------------------------------------------------------------
extern "C" void kernel_launch(void* const* d_in, const int* in_sizes, int n_in,
                              void* d_out, int out_size, void* d_ws, size_t ws_size,
                              hipStream_t stream)
{
  (void)in_sizes; (void)n_in; (void)out_size;
  const float* x      = (const float*)d_in[0];
  const float* W_ih_t = (const float*)d_in[1];
  const float* b_ih_t = (const float*)d_in[3];
  const float* b_hh_t = (const float*)d_in[4];
  const float* W_ih_n = (const float*)d_in[5];
  const float* b_ih_n = (const float*)d_in[7];
  const float* b_hh_n = (const float*)d_in[8];
  float* out = (float*)d_out;

  char* ws = (char*)d_ws;
  _Float16* wsel_hi = (_Float16*)(ws + 0);                   // 192*32*2   = 12288 B
  _Float16* wsel_lo = (_Float16*)(ws + 12288);               // 12288 B
  float*    biasp   = (float*)   (ws + 24576);               // 768 B
  _Float16* wn_hi   = (_Float16*)(ws + 32768);               // 96*8192*2  = 1572864 B
  _Float16* wn_lo   = (_Float16*)(ws + 32768 + 1572864);
  float*    partials= (float*)   (ws + 4194304);             // tsplit*12288*96*4

  // degrade T-split if workspace is small (needs tsplit*4.72MB after 4MB header)
  int tsplit = 8;
  while (tsplit > 1 &&
         4194304ull + (size_t)tsplit * NBROWS * 96 * 4 > ws_size)
    tsplit >>= 1;
  int tchunk = T_STEPS / tsplit;

  k0_prep<<<dim3(512), dim3(256), 0, stream>>>(
      W_ih_t, b_ih_t, b_hh_t, W_ih_n, wsel_hi, wsel_lo, biasp, wn_hi, wn_lo);

  size_t ldsbytes = (size_t)(2 * ROWS_WG * XS_STRIDE +
                             2 * ROWS_WG * TO_STRIDE +
                             2 * 96 * WN_STRIDE) * sizeof(_Float16);  // 84992 B
  k1_time_note<<<dim3(NRT * tsplit), dim3(256), ldsbytes, stream>>>(
      x, wsel_hi, wsel_lo, biasp, wn_hi, wn_lo, partials, tchunk);

  k2_note_out<<<dim3((NBROWS * 24 + 255) / 256), dim3(256), 0, stream>>>(
      partials, b_ih_n, b_hh_n, out, tsplit);
}